// Round 1
// baseline (415.085 us; speedup 1.0000x reference)
//
#include <hip/hip_runtime.h>

typedef __bf16 bf16x8 __attribute__((ext_vector_type(8)));
typedef float f32x4 __attribute__((ext_vector_type(4)));

#define GLD16(gp, lp) __builtin_amdgcn_global_load_lds( \
    (const __attribute__((address_space(1))) void*)(gp), \
    (__attribute__((address_space(3))) void*)(lp), 16, 0, 0)

__device__ __forceinline__ unsigned short f2bf(float f) {
  unsigned int u = __float_as_uint(f);
  u += 0x7FFFu + ((u >> 16) & 1u);   // RNE
  return (unsigned short)(u >> 16);
}

// ---------------- fused f32 -> bf16 cast for all 6 tensors ----------------
// ws elem layout: [0,4M) xq | [4M,8M) xc | [8M,9M) wq | [9M,10M) wk
//                 | [10M,11M) wv | [11M,12M) wo
__global__ __launch_bounds__(256) void cast6(
    const float* __restrict__ xq, const float* __restrict__ xc,
    const float* __restrict__ wq, const float* __restrict__ wk,
    const float* __restrict__ wv, const float* __restrict__ wo,
    unsigned short* __restrict__ d) {
  int i = (blockIdx.x * 256 + threadIdx.x) * 4;  // elem idx, total 12M
  const float* s; int off;
  if      (i < (4 << 20))  { s = xq; off = 0; }
  else if (i < (8 << 20))  { s = xc; off = 4 << 20; }
  else if (i < (9 << 20))  { s = wq; off = 8 << 20; }
  else if (i < (10 << 20)) { s = wk; off = 9 << 20; }
  else if (i < (11 << 20)) { s = wv; off = 10 << 20; }
  else                     { s = wo; off = 11 << 20; }
  float4 v = *(const float4*)(s + (i - off));
  ushort4 o;
  o.x = f2bf(v.x); o.y = f2bf(v.y); o.z = f2bf(v.z); o.w = f2bf(v.w);
  *(ushort4*)(d + i) = o;
}

// ---------------- bf16 GEMM: C[m][n] = sum_k A[m][k]*B[n][k] + bias[n] -----
// 128x128 tile, BK=64, 4 waves 2x2 (64x64 each), global_load_lds staging with
// pre-swizzled source (chunk ^= row&7) so ds_read_b128 frags are conflict-free.
template<int OUTF32>
__device__ __forceinline__ void gemm_body(
    const unsigned short* __restrict__ A, const unsigned short* __restrict__ B,
    const float* __restrict__ bias, void* __restrict__ C,
    int N, int K, int bm, int bn,
    unsigned short* As, unsigned short* Bs) {
  const int t = threadIdx.x;
  const int lane = t & 63, wid = t >> 6;
  const int wm = wid >> 1, wn = wid & 1;
  const int l15 = lane & 15, l4 = lane >> 4, l7 = lane & 7;

  f32x4 acc[4][4];
#pragma unroll
  for (int i = 0; i < 4; ++i)
#pragma unroll
    for (int j = 0; j < 4; ++j) acc[i][j] = (f32x4){0.f, 0.f, 0.f, 0.f};

  const char* Ab = (const char*)A;
  const char* Bb = (const char*)B;
  const int ldb = K * 2;

  for (int kt = 0; kt < K; kt += 64) {
#pragma unroll
    for (int c = 0; c < 4; ++c) {
      int o = c * 4096 + wid * 1024 + lane * 16;
      int row = o >> 7;
      int ch = ((o >> 4) & 7) ^ (row & 7);
      const char* ga = Ab + (size_t)(bm * 128 + row) * ldb + kt * 2 + ch * 16;
      GLD16(ga, (char*)As + c * 4096 + wid * 1024);
      const char* gb = Bb + (size_t)(bn * 128 + row) * ldb + kt * 2 + ch * 16;
      GLD16(gb, (char*)Bs + c * 4096 + wid * 1024);
    }
    __syncthreads();
#pragma unroll
    for (int kk = 0; kk < 2; ++kk) {
      bf16x8 af[4], bfr[4];
#pragma unroll
      for (int mi = 0; mi < 4; ++mi) {
        int row = wm * 64 + mi * 16 + l15;
        int ch = (l4 + 4 * kk) ^ l7;
        af[mi] = *(const bf16x8*)((const char*)As + row * 128 + ch * 16);
      }
#pragma unroll
      for (int ni = 0; ni < 4; ++ni) {
        int row = wn * 64 + ni * 16 + l15;
        int ch = (l4 + 4 * kk) ^ l7;
        bfr[ni] = *(const bf16x8*)((const char*)Bs + row * 128 + ch * 16);
      }
#pragma unroll
      for (int mi = 0; mi < 4; ++mi)
#pragma unroll
        for (int ni = 0; ni < 4; ++ni)
          acc[mi][ni] = __builtin_amdgcn_mfma_f32_16x16x32_bf16(
              af[mi], bfr[ni], acc[mi][ni], 0, 0, 0);
    }
    __syncthreads();
  }

#pragma unroll
  for (int ni = 0; ni < 4; ++ni) {
    int col = bn * 128 + wn * 64 + ni * 16 + l15;
    float bv = bias[col];
#pragma unroll
    for (int mi = 0; mi < 4; ++mi) {
#pragma unroll
      for (int r = 0; r < 4; ++r) {
        int row = bm * 128 + wm * 64 + mi * 16 + l4 * 4 + r;
        float v = acc[mi][ni][r] + bv;
        if (OUTF32) ((float*)C)[(size_t)row * N + col] = v;
        else ((unsigned short*)C)[(size_t)row * N + col] = f2bf(v);
      }
    }
  }
}

// QKV fused: blockIdx.z selects {Q,K,V} projection. bf16 out.
__global__ __launch_bounds__(256) void gemm_qkv(
    const unsigned short* __restrict__ xq, const unsigned short* __restrict__ xc,
    const unsigned short* __restrict__ wq, const unsigned short* __restrict__ wk,
    const unsigned short* __restrict__ wv,
    const float* __restrict__ bq, const float* __restrict__ bk,
    const float* __restrict__ bv,
    unsigned short* __restrict__ Qo, unsigned short* __restrict__ Ko,
    unsigned short* __restrict__ Vo) {
  __shared__ __align__(16) unsigned short As[128 * 64];
  __shared__ __align__(16) unsigned short Bs[128 * 64];
  const unsigned short* A; const unsigned short* B; const float* bias;
  unsigned short* C;
  if (blockIdx.z == 0)      { A = xq; B = wq; bias = bq; C = Qo; }
  else if (blockIdx.z == 1) { A = xc; B = wk; bias = bk; C = Ko; }
  else                      { A = xc; B = wv; bias = bv; C = Vo; }
  gemm_body<0>(A, B, bias, (void*)C, 1024, 1024, blockIdx.y, blockIdx.x, As, Bs);
}

// final projection: f32 out to d_out
__global__ __launch_bounds__(256) void gemm_out(
    const unsigned short* __restrict__ A, const unsigned short* __restrict__ B,
    const float* __restrict__ bias, float* __restrict__ C) {
  __shared__ __align__(16) unsigned short As[128 * 64];
  __shared__ __align__(16) unsigned short Bs[128 * 64];
  gemm_body<1>(A, B, bias, (void*)C, 1024, 1024, blockIdx.y, blockIdx.x, As, Bs);
}

// ---------------- flash attention (causal, 16 heads, Hd=64) ----------------
// grid (S/64, H); 4 waves x 16 q-rows; KV tile = 32.
__global__ __launch_bounds__(256) void flash_attn(
    const unsigned short* __restrict__ Q, const unsigned short* __restrict__ K,
    const unsigned short* __restrict__ V, unsigned short* __restrict__ O) {
  const int h = blockIdx.y;
  const int qb = blockIdx.x;
  const int t = threadIdx.x, lane = t & 63, w = t >> 6;
  const int l15 = lane & 15, l4 = lane >> 4, l7 = lane & 7;
  __shared__ __align__(16) unsigned short Ks[32 * 64];      // [kv][d]
  __shared__ __align__(16) unsigned short Vt[64 * 40];      // [d][kv^swz], pad 40
  __shared__ __align__(16) unsigned short Pl[4][16 * 40];   // per-wave P, pad 40

  const int q0 = qb * 64 + w * 16;

  bf16x8 qf[2];
#pragma unroll
  for (int kk = 0; kk < 2; ++kk)
    qf[kk] = *(const bf16x8*)(Q + (size_t)(q0 + l15) * 1024 + h * 64 + kk * 32 + l4 * 8);

  f32x4 po[4];
#pragma unroll
  for (int dt = 0; dt < 4; ++dt) po[dt] = (f32x4){0.f, 0.f, 0.f, 0.f};
  float m_i[4], l_i[4];
#pragma unroll
  for (int r = 0; r < 4; ++r) { m_i[r] = -1e30f; l_i[r] = 0.f; }

  const int qmax = qb * 64 + 63;
  for (int kv0 = 0; kv0 <= qmax; kv0 += 32) {
    {  // stage K tile [32][64] via global_load_lds, swizzled source
      int o = w * 1024 + lane * 16;
      int row = o >> 7;
      int ch = ((o >> 4) & 7) ^ (row & 7);
      const char* ga = (const char*)K + ((size_t)(kv0 + row) * 1024 + h * 64) * 2 + ch * 16;
      GLD16(ga, (char*)Ks + w * 1024);
    }
    {  // stage V transposed: Vt[d][kv ^ X(d)] = V[kv][d]
      int kv = t >> 3, d0 = (t & 7) * 8;
      bf16x8 v = *(const bf16x8*)(V + (size_t)(kv0 + kv) * 1024 + h * 64 + d0);
#pragma unroll
      for (int j = 0; j < 8; ++j) {
        int d = d0 + j;
        int col = kv ^ (((d >> 3) & 3) << 3);
        Vt[d * 40 + col] = ((const unsigned short*)&v)[j];
      }
    }
    __syncthreads();

    // QK^T: S[16q x 32kv] per wave
    f32x4 sacc[2];
    sacc[0] = (f32x4){0.f, 0.f, 0.f, 0.f};
    sacc[1] = (f32x4){0.f, 0.f, 0.f, 0.f};
#pragma unroll
    for (int kk = 0; kk < 2; ++kk) {
#pragma unroll
      for (int nt = 0; nt < 2; ++nt) {
        int n = nt * 16 + l15;
        int ch = (l4 + 4 * kk) ^ l7;
        bf16x8 kf = *(const bf16x8*)((const char*)Ks + n * 128 + ch * 16);
        sacc[nt] = __builtin_amdgcn_mfma_f32_16x16x32_bf16(qf[kk], kf, sacc[nt], 0, 0, 0);
      }
    }

    // online softmax (rows = l4*4+r, cols = nt*16+l15 within tile)
#pragma unroll
    for (int r = 0; r < 4; ++r) {
      int qi = q0 + l4 * 4 + r;
      float s0 = sacc[0][r] * 0.125f;
      float s1 = sacc[1][r] * 0.125f;
      if (kv0 + l15 > qi) s0 = -1e30f;
      if (kv0 + 16 + l15 > qi) s1 = -1e30f;
      float rm = fmaxf(s0, s1);
      rm = fmaxf(rm, __shfl_xor(rm, 1));
      rm = fmaxf(rm, __shfl_xor(rm, 2));
      rm = fmaxf(rm, __shfl_xor(rm, 4));
      rm = fmaxf(rm, __shfl_xor(rm, 8));
      float mn = fmaxf(m_i[r], rm);
      float corr = __expf(m_i[r] - mn);
      float p0 = __expf(s0 - mn);
      float p1 = __expf(s1 - mn);
      m_i[r] = mn;
      int ql = l4 * 4 + r;
      Pl[w][ql * 40 + l15] = f2bf(p0);
      Pl[w][ql * 40 + 16 + l15] = f2bf(p1);
      float ps = p0 + p1;
      ps += __shfl_xor(ps, 1);
      ps += __shfl_xor(ps, 2);
      ps += __shfl_xor(ps, 4);
      ps += __shfl_xor(ps, 8);
      l_i[r] = l_i[r] * corr + ps;
#pragma unroll
      for (int dt = 0; dt < 4; ++dt) po[dt][r] *= corr;
    }

    // PV: O[16q x 64d] += P[16x32] * V[32x64]
    bf16x8 pf = *(const bf16x8*)((const char*)&Pl[w][0] + l15 * 80 + l4 * 16);
#pragma unroll
    for (int dt = 0; dt < 4; ++dt) {
      int d = dt * 16 + l15;
      int colb = (l4 * 8) ^ (((d >> 3) & 3) << 3);
      bf16x8 vf = *(const bf16x8*)((const char*)Vt + d * 80 + colb * 2);
      po[dt] = __builtin_amdgcn_mfma_f32_16x16x32_bf16(pf, vf, po[dt], 0, 0, 0);
    }
    __syncthreads();
  }

#pragma unroll
  for (int dt = 0; dt < 4; ++dt)
#pragma unroll
    for (int r = 0; r < 4; ++r) {
      int qrow = q0 + l4 * 4 + r;
      int col = h * 64 + dt * 16 + l15;
      O[(size_t)qrow * 1024 + col] = f2bf(po[dt][r] / l_i[r]);
    }
}

// --------------------------------------------------------------------------
extern "C" void kernel_launch(void* const* d_in, const int* in_sizes, int n_in,
                              void* d_out, int out_size, void* d_ws, size_t ws_size,
                              hipStream_t stream) {
  const float* xq = (const float*)d_in[0];
  const float* xc = (const float*)d_in[1];
  // d_in[2] = mask (tril, deterministic) - handled analytically
  const float* wq = (const float*)d_in[3];
  const float* bq = (const float*)d_in[4];
  const float* wk = (const float*)d_in[5];
  const float* bk = (const float*)d_in[6];
  const float* wv = (const float*)d_in[7];
  const float* bv = (const float*)d_in[8];
  const float* wo = (const float*)d_in[9];
  const float* bo = (const float*)d_in[10];

  unsigned short* wsb = (unsigned short*)d_ws;
  unsigned short* xqb = wsb;                    // 4M elems
  unsigned short* xcb = wsb + (4 << 20);        // 4M
  unsigned short* wqb = wsb + (8 << 20);        // 1M
  unsigned short* wkb = wsb + (9 << 20);
  unsigned short* wvb = wsb + (10 << 20);
  unsigned short* wob = wsb + (11 << 20);
  unsigned short* Qb  = wsb + (12 << 20);       // 4M each
  unsigned short* Kb  = wsb + (16 << 20);
  unsigned short* Vb  = wsb + (20 << 20);
  unsigned short* Cb  = wsb + (24 << 20);       // ends at 28M elems = 56 MB

  cast6<<<12288, 256, 0, stream>>>(xq, xc, wq, wk, wv, wo, wsb);

  dim3 gq(1024 / 128, 4096 / 128, 3);
  gemm_qkv<<<gq, 256, 0, stream>>>(xqb, xcb, wqb, wkb, wvb, bq, bk, bv, Qb, Kb, Vb);

  flash_attn<<<dim3(4096 / 64, 16), 256, 0, stream>>>(Qb, Kb, Vb, Cb);

  dim3 go(1024 / 128, 4096 / 128);
  gemm_out<<<go, 256, 0, stream>>>(Cb, wob, bo, (float*)d_out);
}

// Round 2
// 211.719 us; speedup vs baseline: 1.9605x; 1.9605x over previous
//
#include <hip/hip_runtime.h>

typedef __bf16 bf16x8 __attribute__((ext_vector_type(8)));
typedef float f32x4 __attribute__((ext_vector_type(4)));
typedef float f32x16 __attribute__((ext_vector_type(16)));
typedef unsigned int u32x2v __attribute__((ext_vector_type(2)));

#define GLD16(gp, lp) __builtin_amdgcn_global_load_lds( \
    (const __attribute__((address_space(1))) void*)(gp), \
    (__attribute__((address_space(3))) void*)(lp), 16, 0, 0)

__device__ __forceinline__ unsigned short f2bf(float f) {
  unsigned int u = __float_as_uint(f);
  u += 0x7FFFu + ((u >> 16) & 1u);   // RNE
  return (unsigned short)(u >> 16);
}

__device__ __forceinline__ unsigned int cvtpk(float lo, float hi) {
  unsigned int r;
  asm("v_cvt_pk_bf16_f32 %0, %1, %2" : "=v"(r) : "v"(lo), "v"(hi));
  return r;
}

__device__ __forceinline__ float exp2f_(float x) {
#if __has_builtin(__builtin_amdgcn_exp2f)
  return __builtin_amdgcn_exp2f(x);
#else
  float r; asm("v_exp_f32 %0, %1" : "=v"(r) : "v"(x)); return r;
#endif
}

// returns {[A0-31,B0-31], [A32-63,B32-63]}
__device__ __forceinline__ u32x2v pswap(unsigned int a, unsigned int b) {
#if __has_builtin(__builtin_amdgcn_permlane32_swap)
  u32x2v r;
  auto q = __builtin_amdgcn_permlane32_swap(a, b, false, false);
  r[0] = q[0]; r[1] = q[1];
  return r;
#else
  unsigned int pa = (unsigned int)__shfl_xor((int)a, 32);
  unsigned int pb = (unsigned int)__shfl_xor((int)b, 32);
  int hi = (threadIdx.x >> 5) & 1;
  u32x2v r;
  r[0] = hi ? pb : a;
  r[1] = hi ? b : pa;
  return r;
#endif
}

// ---------------- fused f32 -> bf16 cast for all 6 tensors ----------------
__global__ __launch_bounds__(256) void cast6(
    const float* __restrict__ xq, const float* __restrict__ xc,
    const float* __restrict__ wq, const float* __restrict__ wk,
    const float* __restrict__ wv, const float* __restrict__ wo,
    unsigned short* __restrict__ d) {
  int i = (blockIdx.x * 256 + threadIdx.x) * 4;  // elem idx, total 12M
  const float* s; int off;
  if      (i < (4 << 20))  { s = xq; off = 0; }
  else if (i < (8 << 20))  { s = xc; off = 4 << 20; }
  else if (i < (9 << 20))  { s = wq; off = 8 << 20; }
  else if (i < (10 << 20)) { s = wk; off = 9 << 20; }
  else if (i < (11 << 20)) { s = wv; off = 10 << 20; }
  else                     { s = wo; off = 11 << 20; }
  float4 v = *(const float4*)(s + (i - off));
  ushort4 o;
  o.x = f2bf(v.x); o.y = f2bf(v.y); o.z = f2bf(v.z); o.w = f2bf(v.w);
  *(ushort4*)(d + i) = o;
}

// ---------------- bf16 GEMM: C[m][n] = (sum_k A[m][k]*B[n][k] + bias[n])*scale
template<int OUTF32>
__device__ __forceinline__ void gemm_body(
    const unsigned short* __restrict__ A, const unsigned short* __restrict__ B,
    const float* __restrict__ bias, void* __restrict__ C,
    int N, int K, int bm, int bn, float scale,
    unsigned short* As, unsigned short* Bs) {
  const int t = threadIdx.x;
  const int lane = t & 63, wid = t >> 6;
  const int wm = wid >> 1, wn = wid & 1;
  const int l15 = lane & 15, l4 = lane >> 4, l7 = lane & 7;

  f32x4 acc[4][4];
#pragma unroll
  for (int i = 0; i < 4; ++i)
#pragma unroll
    for (int j = 0; j < 4; ++j) acc[i][j] = (f32x4){0.f, 0.f, 0.f, 0.f};

  const char* Ab = (const char*)A;
  const char* Bb = (const char*)B;
  const int ldb = K * 2;

  for (int kt = 0; kt < K; kt += 64) {
#pragma unroll
    for (int c = 0; c < 4; ++c) {
      int o = c * 4096 + wid * 1024 + lane * 16;
      int row = o >> 7;
      int ch = ((o >> 4) & 7) ^ (row & 7);
      const char* ga = Ab + (size_t)(bm * 128 + row) * ldb + kt * 2 + ch * 16;
      GLD16(ga, (char*)As + c * 4096 + wid * 1024);
      const char* gb = Bb + (size_t)(bn * 128 + row) * ldb + kt * 2 + ch * 16;
      GLD16(gb, (char*)Bs + c * 4096 + wid * 1024);
    }
    __syncthreads();
#pragma unroll
    for (int kk = 0; kk < 2; ++kk) {
      bf16x8 af[4], bfr[4];
#pragma unroll
      for (int mi = 0; mi < 4; ++mi) {
        int row = wm * 64 + mi * 16 + l15;
        int ch = (l4 + 4 * kk) ^ l7;
        af[mi] = *(const bf16x8*)((const char*)As + row * 128 + ch * 16);
      }
#pragma unroll
      for (int ni = 0; ni < 4; ++ni) {
        int row = wn * 64 + ni * 16 + l15;
        int ch = (l4 + 4 * kk) ^ l7;
        bfr[ni] = *(const bf16x8*)((const char*)Bs + row * 128 + ch * 16);
      }
#pragma unroll
      for (int mi = 0; mi < 4; ++mi)
#pragma unroll
        for (int ni = 0; ni < 4; ++ni)
          acc[mi][ni] = __builtin_amdgcn_mfma_f32_16x16x32_bf16(
              af[mi], bfr[ni], acc[mi][ni], 0, 0, 0);
    }
    __syncthreads();
  }

#pragma unroll
  for (int ni = 0; ni < 4; ++ni) {
    int col = bn * 128 + wn * 64 + ni * 16 + l15;
    float bv = bias[col];
#pragma unroll
    for (int mi = 0; mi < 4; ++mi) {
#pragma unroll
      for (int r = 0; r < 4; ++r) {
        int row = bm * 128 + wm * 64 + mi * 16 + l4 * 4 + r;
        float v = (acc[mi][ni][r] + bv) * scale;
        if (OUTF32) ((float*)C)[(size_t)row * N + col] = v;
        else ((unsigned short*)C)[(size_t)row * N + col] = f2bf(v);
      }
    }
  }
}

// QKV fused; Q output pre-scaled by 0.125*log2(e) for exp2-domain softmax.
__global__ __launch_bounds__(256) void gemm_qkv(
    const unsigned short* __restrict__ xq, const unsigned short* __restrict__ xc,
    const unsigned short* __restrict__ wq, const unsigned short* __restrict__ wk,
    const unsigned short* __restrict__ wv,
    const float* __restrict__ bq, const float* __restrict__ bk,
    const float* __restrict__ bv,
    unsigned short* __restrict__ Qo, unsigned short* __restrict__ Ko,
    unsigned short* __restrict__ Vo) {
  __shared__ __align__(16) unsigned short As[128 * 64];
  __shared__ __align__(16) unsigned short Bs[128 * 64];
  const unsigned short* A; const unsigned short* B; const float* bias;
  unsigned short* C; float scale;
  if (blockIdx.z == 0)      { A = xq; B = wq; bias = bq; C = Qo; scale = 0.18033688011112042f; }
  else if (blockIdx.z == 1) { A = xc; B = wk; bias = bk; C = Ko; scale = 1.0f; }
  else                      { A = xc; B = wv; bias = bv; C = Vo; scale = 1.0f; }
  gemm_body<0>(A, B, bias, (void*)C, 1024, 1024, blockIdx.y, blockIdx.x, scale, As, Bs);
}

__global__ __launch_bounds__(256) void gemm_out(
    const unsigned short* __restrict__ A, const unsigned short* __restrict__ B,
    const float* __restrict__ bias, float* __restrict__ C) {
  __shared__ __align__(16) unsigned short As[128 * 64];
  __shared__ __align__(16) unsigned short Bs[128 * 64];
  gemm_body<1>(A, B, bias, (void*)C, 1024, 1024, blockIdx.y, blockIdx.x, 1.0f, As, Bs);
}

// ---------------- flash attention, swapped-QK 32x32 structure --------------
// grid (32, 16); 4 waves x 32 q-rows = 128 q/block; KV tile 64.
__global__ __launch_bounds__(256) void flash_attn(
    const unsigned short* __restrict__ Q, const unsigned short* __restrict__ K,
    const unsigned short* __restrict__ V, unsigned short* __restrict__ O) {
  __shared__ __align__(16) char smem[16384];
  char* Ks = smem;            // [64 kv][64 d] bf16, source-swizzled
  char* Vt = smem + 8192;     // [64 d][64 kv] bf16, swizzled

  const int h = blockIdx.y;
  const int qb = (int)gridDim.x - 1 - (int)blockIdx.x;  // longest first
  const int t = threadIdx.x;
  const int lane = t & 63, w = t >> 6;
  const int l31 = lane & 31, hi = lane >> 5;
  const int q0w = qb * 128 + w * 32;
  const int qwmax = q0w + 31;

  // Q fragments (B-operand layout): lane holds Q[q0w+l31][ks*16 + hi*8 + j]
  bf16x8 qf[4];
#pragma unroll
  for (int ks = 0; ks < 4; ++ks)
    qf[ks] = *(const bf16x8*)(Q + (size_t)(q0w + l31) * 1024 + h * 64 + ks * 16 + hi * 8);

  f32x16 po0, po1;
#pragma unroll
  for (int r = 0; r < 16; ++r) { po0[r] = 0.f; po1[r] = 0.f; }
  float m_i = -1e30f, l_i = 0.f;

  const int kvend = qb * 128 + 127;
  for (int kv0 = 0; kv0 <= kvend; kv0 += 64) {
    // ---- stage K [64][64] via global_load_lds, pre-swizzled source ----
#pragma unroll
    for (int i = 0; i < 2; ++i) {
      int id = i * 256 + t;             // 0..511 chunk id
      int row = id >> 3;
      int ch = (id & 7) ^ (row & 7);
      GLD16((const char*)K + (size_t)(kv0 + row) * 2048 + h * 128 + ch * 16,
            Ks + id * 16);
    }
    // ---- stage V transposed: Vt[d][kv], reg path, 4x4 blocks ----
    {
      int d4 = (t & 15) * 4;
      int kvr = (t >> 4) * 4;
      uint2 a[4];
#pragma unroll
      for (int i = 0; i < 4; ++i)
        a[i] = *(const uint2*)(V + (size_t)(kv0 + kvr + i) * 1024 + h * 64 + d4);
#pragma unroll
      for (int j = 0; j < 4; ++j) {
        unsigned sel = (j & 1) ? 0x07060302u : 0x05040100u;
        unsigned s01 = (j < 2) ? __builtin_amdgcn_perm(a[1].x, a[0].x, sel)
                               : __builtin_amdgcn_perm(a[1].y, a[0].y, sel);
        unsigned s23 = (j < 2) ? __builtin_amdgcn_perm(a[3].x, a[2].x, sel)
                               : __builtin_amdgcn_perm(a[3].y, a[2].y, sel);
        int row = d4 + j;
        int sw = (kvr * 2) ^ ((row & 7) << 4);
        *(uint2*)(Vt + row * 128 + sw) = make_uint2(s01, s23);
      }
    }
    __syncthreads();

    if (kv0 <= qwmax) {
      // ---- S^T = K . Q^T : lane owns q = q0w + l31, 32 kv values ----
      f32x16 s0, s1;
#pragma unroll
      for (int r = 0; r < 16; ++r) { s0[r] = 0.f; s1[r] = 0.f; }
#pragma unroll
      for (int ks = 0; ks < 4; ++ks) {
        int c0 = ((ks * 2 + hi) ^ (l31 & 7)) << 4;
        bf16x8 k0 = *(const bf16x8*)(Ks + l31 * 128 + c0);
        bf16x8 k1 = *(const bf16x8*)(Ks + (32 + l31) * 128 + c0);
        s0 = __builtin_amdgcn_mfma_f32_32x32x16_bf16(k0, qf[ks], s0, 0, 0, 0);
        s1 = __builtin_amdgcn_mfma_f32_32x32x16_bf16(k1, qf[ks], s1, 0, 0, 0);
      }
      // ---- causal mask (diagonal tile only; warp-uniform branch) ----
      if (kv0 + 63 > q0w) {
        int q = q0w + l31;
#pragma unroll
        for (int r = 0; r < 16; ++r) {
          int kvi = kv0 + (r & 3) + 8 * (r >> 2) + 4 * hi;
          if (kvi > q) s0[r] = -1e30f;
          if (kvi + 32 > q) s1[r] = -1e30f;
        }
      }
      // ---- online softmax (exp2 domain; Q pre-scaled) ----
      float mt = s0[0];
#pragma unroll
      for (int r = 1; r < 16; ++r) mt = fmaxf(mt, s0[r]);
#pragma unroll
      for (int r = 0; r < 16; ++r) mt = fmaxf(mt, s1[r]);
      u32x2v mw = pswap(__float_as_uint(mt), __float_as_uint(mt));
      mt = fmaxf(__uint_as_float(mw[0]), __uint_as_float(mw[1]));
      float mn = fmaxf(m_i, mt);
      float corr = exp2f_(m_i - mn);
      m_i = mn;
      l_i *= corr;
#pragma unroll
      for (int r = 0; r < 16; ++r) { po0[r] *= corr; po1[r] *= corr; }
      float ps = 0.f;
#pragma unroll
      for (int r = 0; r < 16; ++r) { s0[r] = exp2f_(s0[r] - mn); ps += s0[r]; }
#pragma unroll
      for (int r = 0; r < 16; ++r) { s1[r] = exp2f_(s1[r] - mn); ps += s1[r]; }
      u32x2v sw2 = pswap(__float_as_uint(ps), __float_as_uint(ps));
      l_i += __uint_as_float(sw2[0]) + __uint_as_float(sw2[1]);

      // ---- P -> bf16 B-frags via cvt_pk + permlane32_swap (T12) ----
      unsigned X[16];
#pragma unroll
      for (int i = 0; i < 8; ++i) X[i] = cvtpk(s0[2 * i], s0[2 * i + 1]);
#pragma unroll
      for (int i = 0; i < 8; ++i) X[8 + i] = cvtpk(s1[2 * i], s1[2 * i + 1]);

      // ---- O^T += V^T . P^T ----
#pragma unroll
      for (int kp = 0; kp < 4; ++kp) {
        u32x2v w02 = pswap(X[kp * 4 + 0], X[kp * 4 + 2]);
        u32x2v w13 = pswap(X[kp * 4 + 1], X[kp * 4 + 3]);
        union { unsigned u[4]; bf16x8 v; } pf;
        pf.u[0] = w02[0]; pf.u[1] = w13[0]; pf.u[2] = w02[1]; pf.u[3] = w13[1];
        int cb = kp * 2 + hi;
        {
          int row = l31;
          bf16x8 vf = *(const bf16x8*)(Vt + row * 128 + ((cb ^ (row & 7)) << 4));
          po0 = __builtin_amdgcn_mfma_f32_32x32x16_bf16(vf, pf.v, po0, 0, 0, 0);
        }
        {
          int row = 32 + l31;
          bf16x8 vf = *(const bf16x8*)(Vt + row * 128 + ((cb ^ (row & 7)) << 4));
          po1 = __builtin_amdgcn_mfma_f32_32x32x16_bf16(vf, pf.v, po1, 0, 0, 0);
        }
      }
    }
    __syncthreads();
  }

  // ---- epilogue: normalize, transpose O^T->O through LDS, store ----
  float rinv = 1.0f / l_i;
  int qlocal = w * 32 + l31;
#pragma unroll
  for (int g = 0; g < 4; ++g) {
#pragma unroll
    for (int db = 0; db < 2; ++db) {
      const f32x16& p = db ? po1 : po0;
      unsigned w0 = cvtpk(p[g * 4 + 0] * rinv, p[g * 4 + 1] * rinv);
      unsigned w1 = cvtpk(p[g * 4 + 2] * rinv, p[g * 4 + 3] * rinv);
      int d0 = db * 32 + 8 * g + 4 * hi;
      int byte = qlocal * 128 + ((d0 * 2) ^ ((qlocal & 7) << 4));
      *(uint2*)(smem + byte) = make_uint2(w0, w1);
    }
  }
  __syncthreads();
#pragma unroll
  for (int it = 0; it < 4; ++it) {
    int r = it * 32 + (t >> 3);
    int c = t & 7;
    uint4 val = *(const uint4*)(smem + r * 128 + ((c ^ (r & 7)) << 4));
    *(uint4*)((char*)O + (size_t)(qb * 128 + r) * 2048 + h * 128 + c * 16) = val;
  }
}

// --------------------------------------------------------------------------
extern "C" void kernel_launch(void* const* d_in, const int* in_sizes, int n_in,
                              void* d_out, int out_size, void* d_ws, size_t ws_size,
                              hipStream_t stream) {
  const float* xq = (const float*)d_in[0];
  const float* xc = (const float*)d_in[1];
  const float* wq = (const float*)d_in[3];
  const float* bq = (const float*)d_in[4];
  const float* wk = (const float*)d_in[5];
  const float* bk = (const float*)d_in[6];
  const float* wv = (const float*)d_in[7];
  const float* bv = (const float*)d_in[8];
  const float* wo = (const float*)d_in[9];
  const float* bo = (const float*)d_in[10];

  unsigned short* wsb = (unsigned short*)d_ws;
  unsigned short* xqb = wsb;                    // 4M elems
  unsigned short* xcb = wsb + (4 << 20);        // 4M
  unsigned short* wqb = wsb + (8 << 20);        // 1M
  unsigned short* wkb = wsb + (9 << 20);
  unsigned short* wvb = wsb + (10 << 20);
  unsigned short* wob = wsb + (11 << 20);
  unsigned short* Qb  = wsb + (12 << 20);
  unsigned short* Kb  = wsb + (16 << 20);
  unsigned short* Vb  = wsb + (20 << 20);
  unsigned short* Cb  = wsb + (24 << 20);

  cast6<<<12288, 256, 0, stream>>>(xq, xc, wq, wk, wv, wo, wsb);

  dim3 gq(1024 / 128, 4096 / 128, 3);
  gemm_qkv<<<gq, 256, 0, stream>>>(xqb, xcb, wqb, wkb, wvb, bq, bk, bv, Qb, Kb, Vb);

  flash_attn<<<dim3(32, 16), 256, 0, stream>>>(Qb, Kb, Vb, Cb);

  dim3 go(1024 / 128, 4096 / 128);
  gemm_out<<<go, 256, 0, stream>>>(Cb, wob, bo, (float*)d_out);
}

// Round 3
// 204.519 us; speedup vs baseline: 2.0296x; 1.0352x over previous
//
#include <hip/hip_runtime.h>

typedef __bf16 bf16x8 __attribute__((ext_vector_type(8)));
typedef float f32x4 __attribute__((ext_vector_type(4)));
typedef float f32x16 __attribute__((ext_vector_type(16)));
typedef unsigned int u32x2v __attribute__((ext_vector_type(2)));

#define GLD16(gp, lp) __builtin_amdgcn_global_load_lds( \
    (const __attribute__((address_space(1))) void*)(gp), \
    (__attribute__((address_space(3))) void*)(lp), 16, 0, 0)

__device__ __forceinline__ unsigned short f2bf(float f) {
  unsigned int u = __float_as_uint(f);
  u += 0x7FFFu + ((u >> 16) & 1u);   // RNE
  return (unsigned short)(u >> 16);
}

__device__ __forceinline__ unsigned int cvtpk(float lo, float hi) {
  unsigned int r;
  asm("v_cvt_pk_bf16_f32 %0, %1, %2" : "=v"(r) : "v"(lo), "v"(hi));
  return r;
}

__device__ __forceinline__ float exp2f_(float x) {
#if __has_builtin(__builtin_amdgcn_exp2f)
  return __builtin_amdgcn_exp2f(x);
#else
  float r; asm("v_exp_f32 %0, %1" : "=v"(r) : "v"(x)); return r;
#endif
}

// returns {[A0-31,B0-31], [A32-63,B32-63]}
__device__ __forceinline__ u32x2v pswap(unsigned int a, unsigned int b) {
#if __has_builtin(__builtin_amdgcn_permlane32_swap)
  u32x2v r;
  auto q = __builtin_amdgcn_permlane32_swap(a, b, false, false);
  r[0] = q[0]; r[1] = q[1];
  return r;
#else
  unsigned int pa = (unsigned int)__shfl_xor((int)a, 32);
  unsigned int pb = (unsigned int)__shfl_xor((int)b, 32);
  int hi = (threadIdx.x >> 5) & 1;
  u32x2v r;
  r[0] = hi ? pb : a;
  r[1] = hi ? b : pa;
  return r;
#endif
}

// ---------------- fused f32 -> bf16 cast for all 6 tensors ----------------
__global__ __launch_bounds__(256) void cast6(
    const float* __restrict__ xq, const float* __restrict__ xc,
    const float* __restrict__ wq, const float* __restrict__ wk,
    const float* __restrict__ wv, const float* __restrict__ wo,
    unsigned short* __restrict__ d) {
  int i = (blockIdx.x * 256 + threadIdx.x) * 4;  // elem idx, total 12M
  const float* s; int off;
  if      (i < (4 << 20))  { s = xq; off = 0; }
  else if (i < (8 << 20))  { s = xc; off = 4 << 20; }
  else if (i < (9 << 20))  { s = wq; off = 8 << 20; }
  else if (i < (10 << 20)) { s = wk; off = 9 << 20; }
  else if (i < (11 << 20)) { s = wv; off = 10 << 20; }
  else                     { s = wo; off = 11 << 20; }
  float4 v = *(const float4*)(s + (i - off));
  ushort4 o;
  o.x = f2bf(v.x); o.y = f2bf(v.y); o.z = f2bf(v.z); o.w = f2bf(v.w);
  *(ushort4*)(d + i) = o;
}

// ---------------- bf16 GEMM: C[m][n] = (sum_k A[m][k]*B[n][k] + bias[n])*scale
template<int OUTF32>
__device__ __forceinline__ void gemm_body(
    const unsigned short* __restrict__ A, const unsigned short* __restrict__ B,
    const float* __restrict__ bias, void* __restrict__ C,
    int N, int K, int bm, int bn, float scale,
    unsigned short* As, unsigned short* Bs) {
  const int t = threadIdx.x;
  const int lane = t & 63, wid = t >> 6;
  const int wm = wid >> 1, wn = wid & 1;
  const int l15 = lane & 15, l4 = lane >> 4, l7 = lane & 7;

  f32x4 acc[4][4];
#pragma unroll
  for (int i = 0; i < 4; ++i)
#pragma unroll
    for (int j = 0; j < 4; ++j) acc[i][j] = (f32x4){0.f, 0.f, 0.f, 0.f};

  const char* Ab = (const char*)A;
  const char* Bb = (const char*)B;
  const int ldb = K * 2;

  for (int kt = 0; kt < K; kt += 64) {
#pragma unroll
    for (int c = 0; c < 4; ++c) {
      int o = c * 4096 + wid * 1024 + lane * 16;
      int row = o >> 7;
      int ch = ((o >> 4) & 7) ^ (row & 7);
      const char* ga = Ab + (size_t)(bm * 128 + row) * ldb + kt * 2 + ch * 16;
      GLD16(ga, (char*)As + c * 4096 + wid * 1024);
      const char* gb = Bb + (size_t)(bn * 128 + row) * ldb + kt * 2 + ch * 16;
      GLD16(gb, (char*)Bs + c * 4096 + wid * 1024);
    }
    __syncthreads();
#pragma unroll
    for (int kk = 0; kk < 2; ++kk) {
      bf16x8 af[4], bfr[4];
#pragma unroll
      for (int mi = 0; mi < 4; ++mi) {
        int row = wm * 64 + mi * 16 + l15;
        int ch = (l4 + 4 * kk) ^ l7;
        af[mi] = *(const bf16x8*)((const char*)As + row * 128 + ch * 16);
      }
#pragma unroll
      for (int ni = 0; ni < 4; ++ni) {
        int row = wn * 64 + ni * 16 + l15;
        int ch = (l4 + 4 * kk) ^ l7;
        bfr[ni] = *(const bf16x8*)((const char*)Bs + row * 128 + ch * 16);
      }
#pragma unroll
      for (int mi = 0; mi < 4; ++mi)
#pragma unroll
        for (int ni = 0; ni < 4; ++ni)
          acc[mi][ni] = __builtin_amdgcn_mfma_f32_16x16x32_bf16(
              af[mi], bfr[ni], acc[mi][ni], 0, 0, 0);
    }
    __syncthreads();
  }

#pragma unroll
  for (int ni = 0; ni < 4; ++ni) {
    int col = bn * 128 + wn * 64 + ni * 16 + l15;
    float bv = bias[col];
#pragma unroll
    for (int mi = 0; mi < 4; ++mi) {
#pragma unroll
      for (int r = 0; r < 4; ++r) {
        int row = bm * 128 + wm * 64 + mi * 16 + l4 * 4 + r;
        float v = (acc[mi][ni][r] + bv) * scale;
        if (OUTF32) ((float*)C)[(size_t)row * N + col] = v;
        else ((unsigned short*)C)[(size_t)row * N + col] = f2bf(v);
      }
    }
  }
}

// QKV fused; Q output pre-scaled by 0.125*log2(e) for exp2-domain softmax.
__global__ __launch_bounds__(256) void gemm_qkv(
    const unsigned short* __restrict__ xq, const unsigned short* __restrict__ xc,
    const unsigned short* __restrict__ wq, const unsigned short* __restrict__ wk,
    const unsigned short* __restrict__ wv,
    const float* __restrict__ bq, const float* __restrict__ bk,
    const float* __restrict__ bv,
    unsigned short* __restrict__ Qo, unsigned short* __restrict__ Ko,
    unsigned short* __restrict__ Vo) {
  __shared__ __align__(16) unsigned short As[128 * 64];
  __shared__ __align__(16) unsigned short Bs[128 * 64];
  const unsigned short* A; const unsigned short* B; const float* bias;
  unsigned short* C; float scale;
  if (blockIdx.z == 0)      { A = xq; B = wq; bias = bq; C = Qo; scale = 0.18033688011112042f; }
  else if (blockIdx.z == 1) { A = xc; B = wk; bias = bk; C = Ko; scale = 1.0f; }
  else                      { A = xc; B = wv; bias = bv; C = Vo; scale = 1.0f; }
  gemm_body<0>(A, B, bias, (void*)C, 1024, 1024, blockIdx.y, blockIdx.x, scale, As, Bs);
}

__global__ __launch_bounds__(256) void gemm_out(
    const unsigned short* __restrict__ A, const unsigned short* __restrict__ B,
    const float* __restrict__ bias, float* __restrict__ C) {
  __shared__ __align__(16) unsigned short As[128 * 64];
  __shared__ __align__(16) unsigned short Bs[128 * 64];
  gemm_body<1>(A, B, bias, (void*)C, 1024, 1024, blockIdx.y, blockIdx.x, 1.0f, As, Bs);
}

// ---------------- flash attention, swapped-QK 32x32, double-buffered -------
// grid (32, 16); 4 waves x 32 q-rows = 128 q/block; KV tile 64.
// LDS: Ks[2] @ 0/8K, Vt[2] @ 16K/24K.
__global__ __launch_bounds__(256) void flash_attn(
    const unsigned short* __restrict__ Q, const unsigned short* __restrict__ K,
    const unsigned short* __restrict__ V, unsigned short* __restrict__ O) {
  __shared__ __align__(16) char smem[32768];

  const int h = blockIdx.y;
  const int qb = 31 - (int)blockIdx.x;  // longest first
  const int t = threadIdx.x;
  const int lane = t & 63, w = t >> 6;
  const int l31 = lane & 31, hi = lane >> 5;
  const int q0w = qb * 128 + w * 32;
  const int qwmax = q0w + 31;
  const int ntiles = 2 * (qb + 1);

  // Q fragments (B-operand layout): lane holds Q[q0w+l31][ks*16 + hi*8 + j]
  bf16x8 qf[4];
#pragma unroll
  for (int ks = 0; ks < 4; ++ks)
    qf[ks] = *(const bf16x8*)(Q + (size_t)(q0w + l31) * 1024 + h * 64 + ks * 16 + hi * 8);

  f32x16 po0, po1;
#pragma unroll
  for (int r = 0; r < 16; ++r) { po0[r] = 0.f; po1[r] = 0.f; }
  float m_i = -1e30f, l_i = 0.f;

  const int vd4 = (t & 15) * 4;   // V-transpose: this thread's d block
  const int vkvr = (t >> 4) * 4;  //              and kv block
  uint2 va[4];

  auto stageK = [&](int tile, int buf) {
#pragma unroll
    for (int i = 0; i < 2; ++i) {
      int id = i * 256 + t;
      int row = id >> 3;
      int ch = (id & 7) ^ (row & 7);
      GLD16((const char*)K + (size_t)(tile * 64 + row) * 2048 + h * 128 + ch * 16,
            smem + buf * 8192 + id * 16);
    }
  };
  auto loadV = [&](int tile) {
#pragma unroll
    for (int i = 0; i < 4; ++i)
      va[i] = *(const uint2*)(V + (size_t)(tile * 64 + vkvr + i) * 1024 + h * 64 + vd4);
  };
  auto writeV = [&](int buf) {
    char* Vt = smem + 16384 + buf * 8192;
#pragma unroll
    for (int j = 0; j < 4; ++j) {
      unsigned sel = (j & 1) ? 0x07060302u : 0x05040100u;
      unsigned s01 = (j < 2) ? __builtin_amdgcn_perm(va[1].x, va[0].x, sel)
                             : __builtin_amdgcn_perm(va[1].y, va[0].y, sel);
      unsigned s23 = (j < 2) ? __builtin_amdgcn_perm(va[3].x, va[2].x, sel)
                             : __builtin_amdgcn_perm(va[3].y, va[2].y, sel);
      int row = vd4 + j;
      int sw = (vkvr * 2) ^ (((row >> 2) & 7) << 4);
      *(uint2*)(Vt + row * 128 + sw) = make_uint2(s01, s23);
    }
  };

  // prologue: tile 0 into buffer 0
  stageK(0, 0);
  loadV(0);
  writeV(0);
  __syncthreads();

  for (int it = 0; it < ntiles; ++it) {
    const int c = it & 1;
    const bool pf = (it + 1) < ntiles;
    if (pf) { stageK(it + 1, c ^ 1); loadV(it + 1); }

    const int kv0 = it * 64;
    if (kv0 <= qwmax) {
      const char* Ks = smem + c * 8192;
      const char* Vt = smem + 16384 + c * 8192;
      // ---- S^T = K . Q^T : lane owns q = q0w + l31, 32 kv values ----
      f32x16 s0, s1;
#pragma unroll
      for (int r = 0; r < 16; ++r) { s0[r] = 0.f; s1[r] = 0.f; }
      __builtin_amdgcn_s_setprio(1);
#pragma unroll
      for (int ks = 0; ks < 4; ++ks) {
        int c0 = ((ks * 2 + hi) ^ (l31 & 7)) << 4;
        bf16x8 k0 = *(const bf16x8*)(Ks + l31 * 128 + c0);
        bf16x8 k1 = *(const bf16x8*)(Ks + (32 + l31) * 128 + c0);
        s0 = __builtin_amdgcn_mfma_f32_32x32x16_bf16(k0, qf[ks], s0, 0, 0, 0);
        s1 = __builtin_amdgcn_mfma_f32_32x32x16_bf16(k1, qf[ks], s1, 0, 0, 0);
      }
      __builtin_amdgcn_s_setprio(0);
      // ---- causal mask (diagonal tile only; warp-uniform branch) ----
      if (kv0 + 63 > q0w) {
        int q = q0w + l31;
#pragma unroll
        for (int r = 0; r < 16; ++r) {
          int kvi = kv0 + (r & 3) + 8 * (r >> 2) + 4 * hi;
          if (kvi > q) s0[r] = -1e30f;
          if (kvi + 32 > q) s1[r] = -1e30f;
        }
      }
      // ---- row max: depth-5 tree + cross-half swap ----
      float mx[16];
#pragma unroll
      for (int i = 0; i < 8; ++i) {
        mx[i] = fmaxf(s0[2 * i], s0[2 * i + 1]);
        mx[8 + i] = fmaxf(s1[2 * i], s1[2 * i + 1]);
      }
#pragma unroll
      for (int i = 0; i < 8; ++i) mx[i] = fmaxf(mx[i], mx[8 + i]);
#pragma unroll
      for (int i = 0; i < 4; ++i) mx[i] = fmaxf(mx[i], mx[4 + i]);
      float mt = fmaxf(fmaxf(mx[0], mx[1]), fmaxf(mx[2], mx[3]));
      u32x2v mw = pswap(__float_as_uint(mt), __float_as_uint(mt));
      mt = fmaxf(__uint_as_float(mw[0]), __uint_as_float(mw[1]));
      // ---- defer-rescale (T13): skip O-rescale when growth <= 8 ----
      if (!__all(mt - m_i <= 8.0f)) {
        float mn = fmaxf(m_i, mt);
        float corr = exp2f_(m_i - mn);
        m_i = mn;
        l_i *= corr;
#pragma unroll
        for (int r = 0; r < 16; ++r) { po0[r] *= corr; po1[r] *= corr; }
      }
      // ---- P = exp2(S - m), sum via tree ----
#pragma unroll
      for (int r = 0; r < 16; ++r) s0[r] = exp2f_(s0[r] - m_i);
#pragma unroll
      for (int r = 0; r < 16; ++r) s1[r] = exp2f_(s1[r] - m_i);
      float sx[16];
#pragma unroll
      for (int i = 0; i < 8; ++i) {
        sx[i] = s0[2 * i] + s0[2 * i + 1];
        sx[8 + i] = s1[2 * i] + s1[2 * i + 1];
      }
#pragma unroll
      for (int i = 0; i < 8; ++i) sx[i] += sx[8 + i];
#pragma unroll
      for (int i = 0; i < 4; ++i) sx[i] += sx[4 + i];
      float ps = (sx[0] + sx[1]) + (sx[2] + sx[3]);
      u32x2v sw2 = pswap(__float_as_uint(ps), __float_as_uint(ps));
      l_i += __uint_as_float(sw2[0]) + __uint_as_float(sw2[1]);

      // ---- P -> bf16 B-frags via cvt_pk + permlane32_swap (T12) ----
      unsigned X[16];
#pragma unroll
      for (int i = 0; i < 8; ++i) X[i] = cvtpk(s0[2 * i], s0[2 * i + 1]);
#pragma unroll
      for (int i = 0; i < 8; ++i) X[8 + i] = cvtpk(s1[2 * i], s1[2 * i + 1]);

      // ---- O^T += V^T . P^T ----
#pragma unroll
      for (int kp = 0; kp < 4; ++kp) {
        u32x2v w02 = pswap(X[kp * 4 + 0], X[kp * 4 + 2]);
        u32x2v w13 = pswap(X[kp * 4 + 1], X[kp * 4 + 3]);
        union { unsigned u[4]; bf16x8 v; } pfr;
        pfr.u[0] = w02[0]; pfr.u[1] = w13[0]; pfr.u[2] = w02[1]; pfr.u[3] = w13[1];
        int cb = kp * 2 + hi;
        __builtin_amdgcn_s_setprio(1);
        {
          int row = l31;
          bf16x8 vf = *(const bf16x8*)(Vt + row * 128 + ((cb ^ ((row >> 2) & 7)) << 4));
          po0 = __builtin_amdgcn_mfma_f32_32x32x16_bf16(vf, pfr.v, po0, 0, 0, 0);
        }
        {
          int row = 32 + l31;
          bf16x8 vf = *(const bf16x8*)(Vt + row * 128 + ((cb ^ ((row >> 2) & 7)) << 4));
          po1 = __builtin_amdgcn_mfma_f32_32x32x16_bf16(vf, pfr.v, po1, 0, 0, 0);
        }
        __builtin_amdgcn_s_setprio(0);
      }
    }
    if (pf) writeV(c ^ 1);
    __syncthreads();
  }

  // ---- epilogue: normalize, transpose O^T->O through LDS, store ----
  float rinv = 1.0f / l_i;
  int qlocal = w * 32 + l31;
#pragma unroll
  for (int g = 0; g < 4; ++g) {
#pragma unroll
    for (int db = 0; db < 2; ++db) {
      const f32x16& p = db ? po1 : po0;
      unsigned w0 = cvtpk(p[g * 4 + 0] * rinv, p[g * 4 + 1] * rinv);
      unsigned w1 = cvtpk(p[g * 4 + 2] * rinv, p[g * 4 + 3] * rinv);
      int d0 = db * 32 + 8 * g + 4 * hi;
      int byte = qlocal * 128 + ((d0 * 2) ^ ((qlocal & 7) << 4));
      *(uint2*)(smem + byte) = make_uint2(w0, w1);
    }
  }
  __syncthreads();
#pragma unroll
  for (int it = 0; it < 4; ++it) {
    int r = it * 32 + (t >> 3);
    int c = t & 7;
    uint4 val = *(const uint4*)(smem + r * 128 + ((c ^ (r & 7)) << 4));
    *(uint4*)((char*)O + (size_t)(qb * 128 + r) * 2048 + h * 128 + c * 16) = val;
  }
}

// --------------------------------------------------------------------------
extern "C" void kernel_launch(void* const* d_in, const int* in_sizes, int n_in,
                              void* d_out, int out_size, void* d_ws, size_t ws_size,
                              hipStream_t stream) {
  const float* xq = (const float*)d_in[0];
  const float* xc = (const float*)d_in[1];
  const float* wq = (const float*)d_in[3];
  const float* bq = (const float*)d_in[4];
  const float* wk = (const float*)d_in[5];
  const float* bk = (const float*)d_in[6];
  const float* wv = (const float*)d_in[7];
  const float* bv = (const float*)d_in[8];
  const float* wo = (const float*)d_in[9];
  const float* bo = (const float*)d_in[10];

  unsigned short* wsb = (unsigned short*)d_ws;
  unsigned short* xqb = wsb;                    // 4M elems
  unsigned short* xcb = wsb + (4 << 20);        // 4M
  unsigned short* wqb = wsb + (8 << 20);        // 1M
  unsigned short* wkb = wsb + (9 << 20);
  unsigned short* wvb = wsb + (10 << 20);
  unsigned short* wob = wsb + (11 << 20);
  unsigned short* Qb  = wsb + (12 << 20);
  unsigned short* Kb  = wsb + (16 << 20);
  unsigned short* Vb  = wsb + (20 << 20);
  unsigned short* Cb  = wsb + (24 << 20);

  cast6<<<12288, 256, 0, stream>>>(xq, xc, wq, wk, wv, wo, wsb);

  dim3 gq(1024 / 128, 4096 / 128, 3);
  gemm_qkv<<<gq, 256, 0, stream>>>(xqb, xcb, wqb, wkb, wvb, bq, bk, bv, Qb, Kb, Vb);

  flash_attn<<<dim3(32, 16), 256, 0, stream>>>(Qb, Kb, Vb, Cb);

  dim3 go(1024 / 128, 4096 / 128);
  gemm_out<<<go, 256, 0, stream>>>(Cb, wob, bo, (float*)d_out);
}

// Round 4
// 160.003 us; speedup vs baseline: 2.5942x; 1.2782x over previous
//
#include <hip/hip_runtime.h>

typedef __bf16 bf16x8 __attribute__((ext_vector_type(8)));
typedef float f32x4 __attribute__((ext_vector_type(4)));
typedef float f32x16 __attribute__((ext_vector_type(16)));
typedef unsigned int u32x2v __attribute__((ext_vector_type(2)));

#define GLD16(gp, lp) __builtin_amdgcn_global_load_lds( \
    (const __attribute__((address_space(1))) void*)(gp), \
    (__attribute__((address_space(3))) void*)(lp), 16, 0, 0)

__device__ __forceinline__ unsigned short f2bf(float f) {
  unsigned int u = __float_as_uint(f);
  u += 0x7FFFu + ((u >> 16) & 1u);   // RNE
  return (unsigned short)(u >> 16);
}

__device__ __forceinline__ unsigned int cvtpk(float lo, float hi) {
  unsigned int r;
  asm("v_cvt_pk_bf16_f32 %0, %1, %2" : "=v"(r) : "v"(lo), "v"(hi));
  return r;
}

__device__ __forceinline__ float exp2f_(float x) {
#if __has_builtin(__builtin_amdgcn_exp2f)
  return __builtin_amdgcn_exp2f(x);
#else
  float r; asm("v_exp_f32 %0, %1" : "=v"(r) : "v"(x)); return r;
#endif
}

// returns {[A0-31,B0-31], [A32-63,B32-63]}
__device__ __forceinline__ u32x2v pswap(unsigned int a, unsigned int b) {
#if __has_builtin(__builtin_amdgcn_permlane32_swap)
  u32x2v r;
  auto q = __builtin_amdgcn_permlane32_swap(a, b, false, false);
  r[0] = q[0]; r[1] = q[1];
  return r;
#else
  unsigned int pa = (unsigned int)__shfl_xor((int)a, 32);
  unsigned int pb = (unsigned int)__shfl_xor((int)b, 32);
  int hi = (threadIdx.x >> 5) & 1;
  u32x2v r;
  r[0] = hi ? pb : a;
  r[1] = hi ? b : pa;
  return r;
#endif
}

// ---------------- fused f32 -> bf16 cast for all 6 tensors ----------------
__global__ __launch_bounds__(256) void cast6(
    const float* __restrict__ xq, const float* __restrict__ xc,
    const float* __restrict__ wq, const float* __restrict__ wk,
    const float* __restrict__ wv, const float* __restrict__ wo,
    unsigned short* __restrict__ d) {
  int i = (blockIdx.x * 256 + threadIdx.x) * 4;  // elem idx, total 12M
  const float* s; int off;
  if      (i < (4 << 20))  { s = xq; off = 0; }
  else if (i < (8 << 20))  { s = xc; off = 4 << 20; }
  else if (i < (9 << 20))  { s = wq; off = 8 << 20; }
  else if (i < (10 << 20)) { s = wk; off = 9 << 20; }
  else if (i < (11 << 20)) { s = wv; off = 10 << 20; }
  else                     { s = wo; off = 11 << 20; }
  float4 v = *(const float4*)(s + (i - off));
  ushort4 o;
  o.x = f2bf(v.x); o.y = f2bf(v.y); o.z = f2bf(v.z); o.w = f2bf(v.w);
  *(ushort4*)(d + i) = o;
}

// ---------------- bf16 GEMM: C[m][n] = (sum_k A[m][k]*B[n][k] + bias[n])*scale
template<int OUTF32>
__device__ __forceinline__ void gemm_body(
    const unsigned short* __restrict__ A, const unsigned short* __restrict__ B,
    const float* __restrict__ bias, void* __restrict__ C,
    int N, int K, int bm, int bn, float scale,
    unsigned short* As, unsigned short* Bs) {
  const int t = threadIdx.x;
  const int lane = t & 63, wid = t >> 6;
  const int wm = wid >> 1, wn = wid & 1;
  const int l15 = lane & 15, l4 = lane >> 4, l7 = lane & 7;

  f32x4 acc[4][4];
#pragma unroll
  for (int i = 0; i < 4; ++i)
#pragma unroll
    for (int j = 0; j < 4; ++j) acc[i][j] = (f32x4){0.f, 0.f, 0.f, 0.f};

  const char* Ab = (const char*)A;
  const char* Bb = (const char*)B;
  const int ldb = K * 2;

  for (int kt = 0; kt < K; kt += 64) {
#pragma unroll
    for (int c = 0; c < 4; ++c) {
      int o = c * 4096 + wid * 1024 + lane * 16;
      int row = o >> 7;
      int ch = ((o >> 4) & 7) ^ (row & 7);
      const char* ga = Ab + (size_t)(bm * 128 + row) * ldb + kt * 2 + ch * 16;
      GLD16(ga, (char*)As + c * 4096 + wid * 1024);
      const char* gb = Bb + (size_t)(bn * 128 + row) * ldb + kt * 2 + ch * 16;
      GLD16(gb, (char*)Bs + c * 4096 + wid * 1024);
    }
    __syncthreads();
#pragma unroll
    for (int kk = 0; kk < 2; ++kk) {
      bf16x8 af[4], bfr[4];
#pragma unroll
      for (int mi = 0; mi < 4; ++mi) {
        int row = wm * 64 + mi * 16 + l15;
        int ch = (l4 + 4 * kk) ^ l7;
        af[mi] = *(const bf16x8*)((const char*)As + row * 128 + ch * 16);
      }
#pragma unroll
      for (int ni = 0; ni < 4; ++ni) {
        int row = wn * 64 + ni * 16 + l15;
        int ch = (l4 + 4 * kk) ^ l7;
        bfr[ni] = *(const bf16x8*)((const char*)Bs + row * 128 + ch * 16);
      }
#pragma unroll
      for (int mi = 0; mi < 4; ++mi)
#pragma unroll
        for (int ni = 0; ni < 4; ++ni)
          acc[mi][ni] = __builtin_amdgcn_mfma_f32_16x16x32_bf16(
              af[mi], bfr[ni], acc[mi][ni], 0, 0, 0);
    }
    __syncthreads();
  }

#pragma unroll
  for (int ni = 0; ni < 4; ++ni) {
    int col = bn * 128 + wn * 64 + ni * 16 + l15;
    float bv = bias[col];
#pragma unroll
    for (int mi = 0; mi < 4; ++mi) {
#pragma unroll
      for (int r = 0; r < 4; ++r) {
        int row = bm * 128 + wm * 64 + mi * 16 + l4 * 4 + r;
        float v = (acc[mi][ni][r] + bv) * scale;
        if (OUTF32) ((float*)C)[(size_t)row * N + col] = v;
        else ((unsigned short*)C)[(size_t)row * N + col] = f2bf(v);
      }
    }
  }
}

// QKV fused; Q output pre-scaled by 0.125*log2(e) for exp2-domain softmax.
__global__ __launch_bounds__(256) void gemm_qkv(
    const unsigned short* __restrict__ xq, const unsigned short* __restrict__ xc,
    const unsigned short* __restrict__ wq, const unsigned short* __restrict__ wk,
    const unsigned short* __restrict__ wv,
    const float* __restrict__ bq, const float* __restrict__ bk,
    const float* __restrict__ bv,
    unsigned short* __restrict__ Qo, unsigned short* __restrict__ Ko,
    unsigned short* __restrict__ Vo) {
  __shared__ __align__(16) unsigned short As[128 * 64];
  __shared__ __align__(16) unsigned short Bs[128 * 64];
  const unsigned short* A; const unsigned short* B; const float* bias;
  unsigned short* C; float scale;
  if (blockIdx.z == 0)      { A = xq; B = wq; bias = bq; C = Qo; scale = 0.18033688011112042f; }
  else if (blockIdx.z == 1) { A = xc; B = wk; bias = bk; C = Ko; scale = 1.0f; }
  else                      { A = xc; B = wv; bias = bv; C = Vo; scale = 1.0f; }
  gemm_body<0>(A, B, bias, (void*)C, 1024, 1024, blockIdx.y, blockIdx.x, scale, As, Bs);
}

__global__ __launch_bounds__(256) void gemm_out(
    const unsigned short* __restrict__ A, const unsigned short* __restrict__ B,
    const float* __restrict__ bias, float* __restrict__ C) {
  __shared__ __align__(16) unsigned short As[128 * 64];
  __shared__ __align__(16) unsigned short Bs[128 * 64];
  gemm_body<1>(A, B, bias, (void*)C, 1024, 1024, blockIdx.y, blockIdx.x, 1.0f, As, Bs);
}

// ---------------- flash attention, swapped-QK 32x32, split-KV 8-wave -------
// grid 512 (1D, balanced qb mapping); 8 waves; waves 0-3 = KV half A
// (tiles [0,qb+1)), waves 4-7 = half B (tiles [qb+1,2qb+2)); LDS merge.
// LDS: K[hf][buf] @ (hf*2+buf)*8K in [0,32K); V[hf][buf] @ 32K + same.
// Merge area @ [16K, 52K); transpose area @ [0,16K).
__global__ __launch_bounds__(512, 4) void flash_attn(
    const unsigned short* __restrict__ Q, const unsigned short* __restrict__ K,
    const unsigned short* __restrict__ V, unsigned short* __restrict__ O) {
  __shared__ __align__(16) char smem[65536];

  const int wgid = blockIdx.x;
  int h, qb;
  if (wgid < 256) { h = wgid & 15; qb = wgid >> 4; }
  else            { int r = wgid - 256; h = r & 15; qb = 31 - (r >> 4); }

  const int t = threadIdx.x;
  const int lane = t & 63, w = t >> 6;
  const int hf = w >> 2;          // KV half
  const int s = w & 3;            // q stripe
  const int tl = t & 255;         // thread within half
  const int l31 = lane & 31, hi = lane >> 5;
  const int q0w = qb * 128 + s * 32;
  const int qwmax = q0w + 31;
  const int nh = qb + 1;          // tiles per half
  const int tbase = hf ? nh : 0;

  // Q fragments (B-operand layout): lane holds Q[q0w+l31][ks*16 + hi*8 + j]
  bf16x8 qf[4];
#pragma unroll
  for (int ks = 0; ks < 4; ++ks)
    qf[ks] = *(const bf16x8*)(Q + (size_t)(q0w + l31) * 1024 + h * 64 + ks * 16 + hi * 8);

  f32x16 po0, po1;
#pragma unroll
  for (int r = 0; r < 16; ++r) { po0[r] = 0.f; po1[r] = 0.f; }
  float m_i = -1e30f, l_i = 0.f;

  const int vd4 = (tl & 15) * 4;   // V-transpose: this thread's d block
  const int vkvr = (tl >> 4) * 4;  //              and kv block
  uint2 va[4];

  auto stageK = [&](int tile, int buf) {
#pragma unroll
    for (int i = 0; i < 2; ++i) {
      int id = i * 256 + tl;
      int row = id >> 3;
      int ch = (id & 7) ^ (row & 7);
      GLD16((const char*)K + (size_t)(tile * 64 + row) * 2048 + h * 128 + ch * 16,
            smem + (hf * 2 + buf) * 8192 + id * 16);
    }
  };
  auto loadV = [&](int tile) {
#pragma unroll
    for (int i = 0; i < 4; ++i)
      va[i] = *(const uint2*)(V + (size_t)(tile * 64 + vkvr + i) * 1024 + h * 64 + vd4);
  };
  auto writeV = [&](int buf) {
    char* Vt = smem + 32768 + (hf * 2 + buf) * 8192;
#pragma unroll
    for (int j = 0; j < 4; ++j) {
      unsigned sel = (j & 1) ? 0x07060302u : 0x05040100u;
      unsigned s01 = (j < 2) ? __builtin_amdgcn_perm(va[1].x, va[0].x, sel)
                             : __builtin_amdgcn_perm(va[1].y, va[0].y, sel);
      unsigned s23 = (j < 2) ? __builtin_amdgcn_perm(va[3].x, va[2].x, sel)
                             : __builtin_amdgcn_perm(va[3].y, va[2].y, sel);
      int row = vd4 + j;
      int sw = (vkvr * 2) ^ (((row >> 2) & 7) << 4);
      *(uint2*)(Vt + row * 128 + sw) = make_uint2(s01, s23);
    }
  };

  // prologue: each half stages its tile 0 into its buffer 0
  stageK(tbase, 0);
  loadV(tbase);
  writeV(0);
  __syncthreads();

  for (int it = 0; it < nh; ++it) {
    const int c = it & 1;
    const bool pf = (it + 1) < nh;
    if (pf) { stageK(tbase + it + 1, c ^ 1); loadV(tbase + it + 1); }

    const int kv0 = (tbase + it) * 64;
    if (kv0 <= qwmax) {
      const char* Ks = smem + (hf * 2 + c) * 8192;
      const char* Vt = smem + 32768 + (hf * 2 + c) * 8192;
      // ---- S^T = K . Q^T : lane owns q = q0w + l31, 32 kv values ----
      f32x16 s0, s1;
#pragma unroll
      for (int r = 0; r < 16; ++r) { s0[r] = 0.f; s1[r] = 0.f; }
      __builtin_amdgcn_s_setprio(1);
#pragma unroll
      for (int ks = 0; ks < 4; ++ks) {
        int c0 = ((ks * 2 + hi) ^ (l31 & 7)) << 4;
        bf16x8 k0 = *(const bf16x8*)(Ks + l31 * 128 + c0);
        bf16x8 k1 = *(const bf16x8*)(Ks + (32 + l31) * 128 + c0);
        s0 = __builtin_amdgcn_mfma_f32_32x32x16_bf16(k0, qf[ks], s0, 0, 0, 0);
        s1 = __builtin_amdgcn_mfma_f32_32x32x16_bf16(k1, qf[ks], s1, 0, 0, 0);
      }
      __builtin_amdgcn_s_setprio(0);
      // ---- causal mask (diagonal tile only; warp-uniform branch) ----
      if (kv0 + 63 > q0w) {
        int q = q0w + l31;
#pragma unroll
        for (int r = 0; r < 16; ++r) {
          int kvi = kv0 + (r & 3) + 8 * (r >> 2) + 4 * hi;
          if (kvi > q) s0[r] = -1e30f;
          if (kvi + 32 > q) s1[r] = -1e30f;
        }
      }
      // ---- row max: tree + cross-half swap ----
      float mx[16];
#pragma unroll
      for (int i = 0; i < 8; ++i) {
        mx[i] = fmaxf(s0[2 * i], s0[2 * i + 1]);
        mx[8 + i] = fmaxf(s1[2 * i], s1[2 * i + 1]);
      }
#pragma unroll
      for (int i = 0; i < 8; ++i) mx[i] = fmaxf(mx[i], mx[8 + i]);
#pragma unroll
      for (int i = 0; i < 4; ++i) mx[i] = fmaxf(mx[i], mx[4 + i]);
      float mt = fmaxf(fmaxf(mx[0], mx[1]), fmaxf(mx[2], mx[3]));
      u32x2v mw = pswap(__float_as_uint(mt), __float_as_uint(mt));
      mt = fmaxf(__uint_as_float(mw[0]), __uint_as_float(mw[1]));
      // ---- defer-rescale (T13) ----
      if (!__all(mt - m_i <= 8.0f)) {
        float mn = fmaxf(m_i, mt);
        float corr = exp2f_(m_i - mn);
        m_i = mn;
        l_i *= corr;
#pragma unroll
        for (int r = 0; r < 16; ++r) { po0[r] *= corr; po1[r] *= corr; }
      }
      // ---- P = exp2(S - m), sum via tree ----
#pragma unroll
      for (int r = 0; r < 16; ++r) s0[r] = exp2f_(s0[r] - m_i);
#pragma unroll
      for (int r = 0; r < 16; ++r) s1[r] = exp2f_(s1[r] - m_i);
      float sx[16];
#pragma unroll
      for (int i = 0; i < 8; ++i) {
        sx[i] = s0[2 * i] + s0[2 * i + 1];
        sx[8 + i] = s1[2 * i] + s1[2 * i + 1];
      }
#pragma unroll
      for (int i = 0; i < 8; ++i) sx[i] += sx[8 + i];
#pragma unroll
      for (int i = 0; i < 4; ++i) sx[i] += sx[4 + i];
      float ps = (sx[0] + sx[1]) + (sx[2] + sx[3]);
      u32x2v sw2 = pswap(__float_as_uint(ps), __float_as_uint(ps));
      l_i += __uint_as_float(sw2[0]) + __uint_as_float(sw2[1]);

      // ---- P -> bf16 B-frags via cvt_pk + permlane32_swap (T12) ----
      unsigned X[16];
#pragma unroll
      for (int i = 0; i < 8; ++i) X[i] = cvtpk(s0[2 * i], s0[2 * i + 1]);
#pragma unroll
      for (int i = 0; i < 8; ++i) X[8 + i] = cvtpk(s1[2 * i], s1[2 * i + 1]);

      // ---- O^T += V^T . P^T ----
#pragma unroll
      for (int kp = 0; kp < 4; ++kp) {
        u32x2v w02 = pswap(X[kp * 4 + 0], X[kp * 4 + 2]);
        u32x2v w13 = pswap(X[kp * 4 + 1], X[kp * 4 + 3]);
        union { unsigned u[4]; bf16x8 v; } pfr;
        pfr.u[0] = w02[0]; pfr.u[1] = w13[0]; pfr.u[2] = w02[1]; pfr.u[3] = w13[1];
        int cb = kp * 2 + hi;
        __builtin_amdgcn_s_setprio(1);
        {
          int row = l31;
          bf16x8 vf = *(const bf16x8*)(Vt + row * 128 + ((cb ^ ((row >> 2) & 7)) << 4));
          po0 = __builtin_amdgcn_mfma_f32_32x32x16_bf16(vf, pfr.v, po0, 0, 0, 0);
        }
        {
          int row = 32 + l31;
          bf16x8 vf = *(const bf16x8*)(Vt + row * 128 + ((cb ^ ((row >> 2) & 7)) << 4));
          po1 = __builtin_amdgcn_mfma_f32_32x32x16_bf16(vf, pfr.v, po1, 0, 0, 0);
        }
        __builtin_amdgcn_s_setprio(0);
      }
    }
    if (pf) writeV(c ^ 1);
    __syncthreads();
  }

  // ---- split-KV merge: high half publishes (po, m, l); low half merges ----
  char* mrg = smem + 16384;  // [16K, 52K): 4 stripes x 64 lanes x 144 B
  if (hf) {
    char* mb = mrg + s * 9216 + lane * 144;
    *(f32x16*)(mb) = po0;
    *(f32x16*)(mb + 64) = po1;
    *(float*)(mb + 128) = m_i;
    *(float*)(mb + 132) = l_i;
  }
  __syncthreads();
  float rinv = 0.f;
  if (!hf) {
    char* mb = mrg + s * 9216 + lane * 144;
    float pm = *(float*)(mb + 128);
    float plv = *(float*)(mb + 132);
    float M = fmaxf(m_i, pm);
    float wA = exp2f_(m_i - M);
    float wB = exp2f_(pm - M);
    float lt = l_i * wA + plv * wB;
    rinv = 1.0f / lt;
    f32x16 qa = *(const f32x16*)(mb);
#pragma unroll
    for (int r = 0; r < 16; ++r) po0[r] = po0[r] * wA + qa[r] * wB;
    f32x16 qbv = *(const f32x16*)(mb + 64);
#pragma unroll
    for (int r = 0; r < 16; ++r) po1[r] = po1[r] * wA + qbv[r] * wB;

    // normalize + transpose-write bf16 into [0,16K)
    int qlocal = s * 32 + l31;
#pragma unroll
    for (int g = 0; g < 4; ++g) {
#pragma unroll
      for (int db = 0; db < 2; ++db) {
        const f32x16& p = db ? po1 : po0;
        unsigned w0 = cvtpk(p[g * 4 + 0] * rinv, p[g * 4 + 1] * rinv);
        unsigned w1 = cvtpk(p[g * 4 + 2] * rinv, p[g * 4 + 3] * rinv);
        int d0 = db * 32 + 8 * g + 4 * hi;
        int byte = qlocal * 128 + ((d0 * 2) ^ ((qlocal & 7) << 4));
        *(uint2*)(smem + byte) = make_uint2(w0, w1);
      }
    }
  }
  __syncthreads();
  if (!hf) {
#pragma unroll
    for (int it = 0; it < 4; ++it) {
      int r = it * 32 + (t >> 3);
      int c = t & 7;
      uint4 val = *(const uint4*)(smem + r * 128 + ((c ^ (r & 7)) << 4));
      *(uint4*)((char*)O + (size_t)(qb * 128 + r) * 2048 + h * 128 + c * 16) = val;
    }
  }
}

// --------------------------------------------------------------------------
extern "C" void kernel_launch(void* const* d_in, const int* in_sizes, int n_in,
                              void* d_out, int out_size, void* d_ws, size_t ws_size,
                              hipStream_t stream) {
  const float* xq = (const float*)d_in[0];
  const float* xc = (const float*)d_in[1];
  const float* wq = (const float*)d_in[3];
  const float* bq = (const float*)d_in[4];
  const float* wk = (const float*)d_in[5];
  const float* bk = (const float*)d_in[6];
  const float* wv = (const float*)d_in[7];
  const float* bv = (const float*)d_in[8];
  const float* wo = (const float*)d_in[9];
  const float* bo = (const float*)d_in[10];

  unsigned short* wsb = (unsigned short*)d_ws;
  unsigned short* xqb = wsb;                    // 4M elems
  unsigned short* xcb = wsb + (4 << 20);        // 4M
  unsigned short* wqb = wsb + (8 << 20);        // 1M
  unsigned short* wkb = wsb + (9 << 20);
  unsigned short* wvb = wsb + (10 << 20);
  unsigned short* wob = wsb + (11 << 20);
  unsigned short* Qb  = wsb + (12 << 20);
  unsigned short* Kb  = wsb + (16 << 20);
  unsigned short* Vb  = wsb + (20 << 20);
  unsigned short* Cb  = wsb + (24 << 20);

  cast6<<<12288, 256, 0, stream>>>(xq, xc, wq, wk, wv, wo, wsb);

  dim3 gq(1024 / 128, 4096 / 128, 3);
  gemm_qkv<<<gq, 256, 0, stream>>>(xqb, xcb, wqb, wkb, wvb, bq, bk, bv, Qb, Kb, Vb);

  flash_attn<<<512, 512, 0, stream>>>(Qb, Kb, Vb, Cb);

  dim3 go(1024 / 128, 4096 / 128);
  gemm_out<<<go, 256, 0, stream>>>(Cb, wob, bo, (float*)d_out);
}